// Round 7
// baseline (207.186 us; speedup 1.0000x reference)
//
#include <hip/hip_runtime.h>

typedef float f32x4 __attribute__((ext_vector_type(4)));

#define T_LEN 2048
#define GROUP 16
#define NG    (T_LEN / GROUP)   /* 128 groups */
#define NT    (NG + 4)          /* depth-5 pipeline: 132 ticks */
#define CH    12                /* 16B chunks per lane per group */
#define KH    28.853901f        /* 20*log2(e): h(x) = 1/(1+exp2(-KH*x)) */
#define L2E   1.4426950408889634f

__device__ __forceinline__ float hs_neg(float negKx) {
    float e = __builtin_amdgcn_exp2f(negKx);
    return __builtin_amdgcn_rcpf(1.0f + e);
}

#define WAITV(N) asm volatile("s_waitcnt vmcnt(" #N ")" ::: "memory")
/* raw barrier (NOT __syncthreads: that drains vmcnt(0), killing DMA prefetch) */
#define TICK_BARRIER() do {                                   \
    asm volatile("s_waitcnt lgkmcnt(0)" ::: "memory");        \
    __builtin_amdgcn_s_barrier();                             \
    __builtin_amdgcn_sched_barrier(0); } while (0)

#define DMA_GROUP(SLOT, G) do {                                                \
    const float* g_ = row + (size_t)(G) * (3 * GROUP);                         \
    _Pragma("unroll")                                                          \
    for (int j_ = 0; j_ < CH; ++j_) {                                          \
        __builtin_amdgcn_global_load_lds(                                      \
            (const __attribute__((address_space(1))) void*)(g_ + 4 * j_),      \
            (__attribute__((address_space(3))) void*)&s_in[SLOT][j_][0],       \
            16, 0, 0);                                                         \
    } } while (0)

/* sigma(20*x) via LDS table: z = 20x over [-1, 12], 16 entries/unit, lerp.
   All table arguments are provably >= -0.03 (y,rem,u >= -0.014, ps >= -0.03),
   so the low clamp at z=-1 is never hit with meaningful error; high clamp at
   z=12 has |err| <= 6.1e-6. Interp error <= 4.7e-5. */
#define LOOKUP(RES, X) do {                                                    \
    float if_ = fmaf((X), 320.0f, 16.0f);                                      \
    if_ = fminf(fmaxf(if_, 0.0f), 207.9985f);                                  \
    int i_ = (int)if_;                                                         \
    float fr_ = if_ - (float)i_;                                               \
    float s0_ = s_tab[i_], s1_ = s_tab[i_ + 1];                                \
    (RES) = fmaf(fr_, s1_ - s0_, s0_); } while (0)

__global__ __launch_bounds__(256, 1)
void xaj_pipe5_kernel(const float* __restrict__ inp,
                      const float* __restrict__ p_wum,
                      const float* __restrict__ p_wlm,
                      const float* __restrict__ p_wdm,
                      const float* __restrict__ p_c,
                      const float* __restrict__ p_b,
                      const float* __restrict__ p_k1,
                      const float* __restrict__ p_k2,
                      const float* __restrict__ p_k3,
                      float* __restrict__ out)
{
    __shared__ f32x4 s_in [3][CH][64];        /* 36 KB: input ring-3 (W0 only) */
    __shared__ float s_tab[212];              /* sigma table */
    __shared__ float s_y  [2][GROUP][64];     /* W0 -> WS (y = t(v)) */
    __shared__ float s_rem[2][GROUP][64];     /* WS -> W1 */
    __shared__ float s_d1 [4][GROUP][64];     /* W0 -> W1 (2 ticks) */
    __shared__ float s_u  [2][GROUP][64];     /* W1 -> W2 */
    __shared__ float s_d2 [2][GROUP][64];     /* W1 -> W2 */
    __shared__ float s_wd [2][GROUP][64];     /* W2 -> WS */
    __shared__ float s_wu [8][GROUP][64];     /* W0 -> WS (4 ticks) */
    __shared__ float s_p  [8][GROUP][64];     /* W0 -> WS (4 ticks) */

    const int lane  = threadIdx.x & 63;
    const int wv    = threadIdx.x >> 6;
    const int chain = blockIdx.x * 64 + lane;
    const float* __restrict__ row = inp + (size_t)chain * (3 * T_LEN);
    float* __restrict__ orow      = out + (size_t)chain * T_LEN;

    const float wum = p_wum[0], wlm = p_wlm[0], wdm = p_wdm[0];
    const float cc  = p_c[0],   bb  = p_b[0];
    const float k1  = p_k1[0],  k2  = p_k2[0],  k3 = p_k3[0];

    /* runoff_production called as (wu, wd, wl, p, wum, wdm, wlm, b, c) */
    const float w_total = (wum * 19.9f + 0.1f)
                        + (wdm * 30.0f + 60.0f)
                        + (wlm * 60.0f + 60.0f);
    const float inv_wt = 1.0f / w_total;
    const float c_s = cc * 0.19f + 0.01f;
    const float b_s = bb * 0.3f  + 0.1f;
    const float k1s = k1 * 0.69f + 0.01f;
    const float k2s = k2 * 0.69f + 0.01f;
    const float k3s = k3 * 0.89f + 0.01f;
    const float Kq = k1s + 0.5f * k2s * (1.0f - k1s)
                   + 0.25f * k3s * (1.0f - k1s) * (1.0f - k2s);

    /* sigma table build: entry i -> z = (i-16)/16, sigma(z) = 1/(1+exp2(-z*L2E)) */
    {
        int tid = threadIdx.x;
        if (tid < 209) {
            float z = (float)(tid - 16) * 0.0625f;
            s_tab[tid] = hs_neg(-z * L2E);
        }
    }

    float wu = 0.0f, wl = 0.0f, wd = 0.0f;   /* per-wave scan state */

    if (wv == 0) {
        DMA_GROUP(0, 0);
        DMA_GROUP(1, 1);
    }
    TICK_BARRIER();   /* table + DMA issue ordering (does not drain vmcnt) */

    /* tick t: W0 -> group t | WS.rem -> t-1 | W1 -> t-2 | W2 -> t-3 | WS.out -> t-4 */
    for (int t = 0; t < NT; ++t) {
        if (wv == 0) {
            if (t < NG) {
                if (t < NG - 1) { WAITV(12); } else { WAITV(0); }
                __builtin_amdgcn_sched_barrier(0);
                f32x4 fv[CH];
                const int s3 = t % 3;
#pragma unroll
                for (int j = 0; j < CH; ++j) fv[j] = s_in[s3][j][lane];
                if (t + 2 < NG) DMA_GROUP((t + 2) % 3, t + 2);
#pragma unroll
                for (int j = 0; j < GROUP; ++j) {
                    float pet = fv[(3*j)   >> 2][(3*j)   & 3];
                    float p   = fv[(3*j+2) >> 2][(3*j+2) & 3];
                    float v   = pet - wu;
                    float sv  = hs_neg(-KH * v);      /* sigma(20v), chained */
                    float tv  = v * sv;               /* t(v) = y = pet-et1 */
                    float pp  = p - pet;              /* off-chain */
                    float d1  = pp + tv;
                    wu += d1;
                    s_y [t & 1][j][lane] = tv;
                    s_d1[t & 3][j][lane] = d1;
                    s_wu[t & 7][j][lane] = wu;
                    s_p [t & 7][j][lane] = p;
                }
            }
        } else if (wv == 1) {
            const int g = t - 2;
            if (g >= 0 && g < NG) {
#pragma unroll
                for (int j = 0; j < GROUP; ++j) {
                    float rem  = s_rem[g & 1][j][lane];
                    float d1   = s_d1 [g & 3][j][lane];
                    float hrem;                      /* sigma(20*rem), stateless */
                    LOOKUP(hrem, rem);
                    float q1 = fmaf(KH, wl, -KH * rem);   /* chain head */
                    float e1 = __builtin_amdgcn_exp2f(q1);
                    float sw = __builtin_amdgcn_rcpf(1.0f + e1); /* sigma(20(rem-wl)) */
                    float w  = rem - wl;
                    float tw = w * sw;                    /* t(rem-wl) */
                    float A  = fmaf(-hrem, rem, wl + d1); /* off-chain */
                    float hr = hrem * rem;
                    float et2 = fmaf(-hrem, tw, hr);      /* hrem*(rem-tw) */
                    wl = fmaf(hrem, tw, A);               /* wl + d1 - et2 */
                    float u  = rem - et2;
                    float d2 = d1 - et2;
                    s_u [g & 1][j][lane] = u;
                    s_d2[g & 1][j][lane] = d2;
                }
            }
        } else if (wv == 2) {
            const int g = t - 3;
            if (g >= 0 && g < NG) {
#pragma unroll
                for (int j = 0; j < GROUP; ++j) {
                    float u  = s_u [g & 1][j][lane];
                    float d2 = s_d2[g & 1][j][lane];
                    float hu;                        /* sigma(20u), stateless */
                    LOOKUP(hu, u);
                    float q2 = fmaf(KH, wd, -KH * u);     /* chain head */
                    float e2 = __builtin_amdgcn_exp2f(q2);
                    float sq = __builtin_amdgcn_rcpf(1.0f + e2); /* sigma(20(u-wd)) */
                    float tq = (u - wd) * sq;             /* t(u-wd) */
                    float A2 = fmaf(-hu, u, wd + d2);     /* off-chain */
                    wd = fmaf(hu, tq, A2);                /* wd + d2 - et3 */
                    s_wd[g & 1][j][lane] = wd;
                }
            }
        } else {
            /* WS: stateless sigma work via table */
            const int g1 = t - 1;
            if (g1 >= 0 && g1 < NG) {
#pragma unroll
                for (int j = 0; j < GROUP; ++j) {
                    float y = s_y[g1 & 1][j][lane];
                    float sy;
                    LOOKUP(sy, y);
                    s_rem[g1 & 1][j][lane] = y * sy;      /* rem = t(y) */
                }
            }
            const int g4 = t - 4;
            if (g4 >= 0) {
                float qv[GROUP];
#pragma unroll
                for (int j = 0; j < GROUP; ++j) {
                    float wuv = s_wu[g4 & 7][j][lane];
                    float wdv = s_wd[g4 & 1][j][lane];
                    float p   = s_p [g4 & 7][j][lane];
                    float ru = wuv * inv_wt;
                    float rd = wdv * inv_wt;
                    float s2 = fmaf(c_s * ru, ru, (b_s * rd) * rd);
                    float ps = p - s2;
                    float so;
                    LOOKUP(so, ps);
                    qv[j] = ps * so * Kq;                 /* t(ps) * Kq */
                }
                f32x4* o4 = (f32x4*)(orow + (size_t)g4 * GROUP);
#pragma unroll
                for (int i = 0; i < GROUP / 4; ++i) {
                    f32x4 q = {qv[4*i], qv[4*i+1], qv[4*i+2], qv[4*i+3]};
                    o4[i] = q;
                }
            }
        }
        TICK_BARRIER();
    }
}

extern "C" void kernel_launch(void* const* d_in, const int* in_sizes, int n_in,
                              void* d_out, int out_size, void* d_ws, size_t ws_size,
                              hipStream_t stream) {
    const float* inp = (const float*)d_in[0];
    const int B = out_size / T_LEN;            // 4096
    dim3 block(256), grid(B / 64);
    xaj_pipe5_kernel<<<grid, block, 0, stream>>>(
        inp,
        (const float*)d_in[1],  // wum
        (const float*)d_in[2],  // wlm
        (const float*)d_in[3],  // wdm
        (const float*)d_in[4],  // c
        (const float*)d_in[5],  // b
        (const float*)d_in[6],  // k1
        (const float*)d_in[7],  // k2
        (const float*)d_in[8],  // k3
        (float*)d_out);
}